// Round 2
// baseline (455.055 us; speedup 1.0000x reference)
//
#include <hip/hip_runtime.h>
#include <cstdint>

typedef __attribute__((ext_vector_type(8))) short bf16x8;
typedef __attribute__((ext_vector_type(4))) float f32x4;

__device__ __forceinline__ uint32_t bf16_rne(float f) {
    uint32_t u = __float_as_uint(f);
    u += 0x7FFFu + ((u >> 16) & 1u);
    return u >> 16;
}
__device__ __forceinline__ float bf16_f32(uint32_t h) {
    return __uint_as_float(h << 16);
}

__device__ __forceinline__ float tanh_fast(float x) {
    float e = __builtin_amdgcn_exp2f(x * 2.8853900817779268f);
    return fmaf(-2.0f, __builtin_amdgcn_rcpf(e + 1.0f), 1.0f);
}

__device__ __forceinline__ float sel4(float a, float b, float c, float d, int T) {
    float x = (T & 1) ? b : a;
    float y = (T & 1) ? d : c;
    return (T & 2) ? y : x;
}

// ---- prep: W1 (20x64 k-major) -> MFMA A-frag layout, split bf16 hi+lo ----
__global__ __launch_bounds__(256) void prep_kernel(
    const float* __restrict__ W1_0, const float* __restrict__ W1_1,
    const float* __restrict__ W1_2, uint32_t* __restrict__ wf) {
    int m = blockIdx.x;
    const float* W1 = (m == 0) ? W1_0 : (m == 1) ? W1_1 : W1_2;
    int tid = threadIdx.x;
    int Ht = tid >> 6, lane = tid & 63;
    int n = (lane & 15) + 16 * Ht;
    int kb = (lane >> 4) * 8;
    uint32_t dh[4], dl[4];
#pragma unroll
    for (int q = 0; q < 4; ++q) {
        int k0 = kb + 2 * q, k1 = k0 + 1;
        float w0 = (k0 < 20) ? W1[k0 * 64 + n] : 0.0f;
        float w1 = (k1 < 20) ? W1[k1 * 64 + n] : 0.0f;
        uint32_t h0 = bf16_rne(w0), h1 = bf16_rne(w1);
        uint32_t l0 = bf16_rne(w0 - bf16_f32(h0));
        uint32_t l1 = bf16_rne(w1 - bf16_f32(h1));
        dh[q] = h0 | (h1 << 16);
        dl[q] = l0 | (l1 << 16);
    }
    size_t idx = ((size_t)(m * 4 + Ht) * 64 + lane) * 4;
    *(uint4*)(wf + idx)        = make_uint4(dh[0], dh[1], dh[2], dh[3]);
    *(uint4*)(wf + 3072 + idx) = make_uint4(dl[0], dl[1], dl[2], dl[3]);
}

// Wave-independent version: wave-local bucket sort via ballot/popc (no LDS
// atomics, no perm arrays), single-phase hi+lo feature staging in a per-wave
// 64-row LDS region, flux routed back by one dynamic __shfl.
// ZERO __syncthreads -> waves slip freely; barrier-drain stalls eliminated.
// Row stride = 36 dwords (144 B): bank base (9r+hi)%8 uniform for both the
// 8x ds_write_b128 and 8x ds_read_b128 -> minimum-cycle LDS access.
__global__ __launch_bounds__(256, 4) void riemann_fused(
    const float* __restrict__ P, const float* __restrict__ U,
    const float* __restrict__ F, const float* __restrict__ cmax,
    const float* __restrict__ cmin,
    const float* __restrict__ b1_ds, const float* __restrict__ W2_ds, const float* __restrict__ b2_ds,
    const float* __restrict__ b1_dr, const float* __restrict__ W2_dr, const float* __restrict__ b2_dr,
    const float* __restrict__ b1_rs, const float* __restrict__ W2_rs, const float* __restrict__ b2_rs,
    const uint32_t* __restrict__ wf,
    float* __restrict__ out, int N) {
    __shared__ __align__(16) uint32_t sm[256 * 36];   // 36 KiB, per-wave 64-row slabs

    int tid = threadIdx.x;
    int wv = tid >> 6, lane = tid & 63;
    int hi = lane >> 4, lo16 = lane & 15;
    int cell = blockIdx.x * 256 + tid;
    bool valid = cell < N;
    int cg = valid ? cell : N - 1;

    // ---- per-cell prologue (identical to verified baseline) ----
    const float2* P2 = (const float2*)P + (size_t)cg * 3;
    const float2* U2 = (const float2*)U + (size_t)cg * 3;
    const float2* F2 = (const float2*)F + (size_t)cg * 3;
    float2 Pa = P2[0], Pb = P2[1], Pc = P2[2];
    float2 Ua = U2[0], Ub = U2[1], Uc = U2[2];
    float2 Fa = F2[0], Fb = F2[1], Fc = F2[2];
    float cm = cmax[cg];
    float cn = cmin[cg];

    bool flip = Pb.y > Pb.x;
    float fe[20];
    fe[0]  = flip ?  Pa.y :  Pa.x;
    fe[1]  = flip ?  Pa.x :  Pa.y;
    fe[2]  = flip ?  Pb.y :  Pb.x;
    fe[3]  = flip ?  Pb.x :  Pb.y;
    fe[4]  = flip ? -Pc.y :  Pc.x;
    fe[5]  = flip ? -Pc.x :  Pc.y;
    fe[6]  = flip ?  Ua.y :  Ua.x;
    fe[7]  = flip ?  Ua.x :  Ua.y;
    fe[8]  = flip ?  Ub.y :  Ub.x;
    fe[9]  = flip ?  Ub.x :  Ub.y;
    fe[10] = flip ? -Uc.y :  Uc.x;
    fe[11] = flip ? -Uc.x :  Uc.y;
    fe[12] = flip ? -Fa.y :  Fa.x;
    fe[13] = flip ? -Fa.x :  Fa.y;
    fe[14] = flip ? -Fb.y :  Fb.x;
    fe[15] = flip ? -Fb.x :  Fb.y;
    fe[16] = flip ?  Fc.y :  Fc.x;
    fe[17] = flip ?  Fc.x :  Fc.y;
    fe[18] = cm;
    fe[19] = cn;

    // cont: exact f64 compares
    double dd0 = fabs((double)fe[1] - (double)fe[0]);
    double dd1 = fabs((double)fe[3] - (double)fe[2]);
    double dd2 = fabs((double)fe[5] - (double)fe[4]);
    bool cont = fmax(fmax(dd0, dd1), dd2) < 0.005;

    // HLLE
    float inv = __builtin_amdgcn_rcpf(cm - cn);
    float cmn = cm * cn;
    float hl0 = (cm * fe[12] - cn * fe[13] + cmn * (fe[7]  - fe[6]))  * inv;
    float hl1 = (cm * fe[14] - cn * fe[15] + cmn * (fe[9]  - fe[8]))  * inv;
    float hl2 = (cm * fe[16] - cn * fe[17] + cmn * (fe[11] - fe[10])) * inv;

    // classification: f32 fast path + eps-guarded exact f64 fallback
    float c0f = __builtin_amdgcn_sqrtf(1.6666666f * fe[2] * __builtin_amdgcn_rcpf(fe[0]));
    float c1f = __builtin_amdgcn_sqrtf(1.6666666f * fe[3] * __builtin_amdgcn_rcpf(fe[1]));
    float dvf = fe[5] - fe[4];
    float numf = c0f + c1f - (1.0f / 3.0f) * dvf;
    float pz0 = __builtin_amdgcn_exp2f(-0.2f * __builtin_amdgcn_logf(fe[2]));
    float pz1 = __builtin_amdgcn_exp2f(-0.2f * __builtin_amdgcn_logf(fe[3]));
    float denf = c0f * pz0 + c1f * pz1;
    float tq = fmaxf(numf * __builtin_amdgcn_rcpf(denf), 1e-8f);
    float t2 = tq * tq;
    float psf = t2 * t2 * tq;
    float pminf = fminf(fe[2], fe[3]);
    float pmaxf = fmaxf(fe[2], fe[3]);
    float csum3 = 3.0f * (c0f + c1f);
    float vs = dvf - csum3;
    int label = (vs >= 0.0f) ? 3 : (psf < pminf ? 1 : (psf > pmaxf ? 0 : 2));

    const float eps = 2e-4f;
    bool amb = (fabsf(psf - pminf) <= eps * pminf) ||
               (fabsf(psf - pmaxf) <= eps * pmaxf) ||
               (fabsf(vs) <= eps * (fabsf(dvf) + csum3));
    if (__builtin_expect(amb, 0)) {
        double rho0 = (double)fe[0], rho1 = (double)fe[1];
        double p0   = (double)fe[2], p1   = (double)fe[3];
        double v0   = (double)fe[4], v1   = (double)fe[5];
        const double g = 5.0 / 3.0;
        double c0 = sqrt(g * p0 / rho0);
        double c1 = sqrt(g * p1 / rho1);
        double dv = v1 - v0;
        double z = (g - 1.0) / (2.0 * g);
        double num = c0 + c1 - 0.5 * (g - 1.0) * dv;
        double den = c0 / pow(p0, z) + c1 / pow(p1, z);
        double ps = pow(fmax(num / den, 1e-8), 1.0 / z);
        bool vacd = dv >= 2.0 / (g - 1.0) * (c0 + c1);
        label = vacd ? 3 : (ps < fmin(p0, p1) ? 1 : (ps > fmax(p0, p1) ? 0 : 2));
    }
    // work-label: 3 = trivial (cont override or vacuum) -> no MLP needed
    int wl = (!valid || cont || label == 3) ? 3 : label;

    // ---- wave-local bucket sort: ballots + popc, all in registers ----
    uint64_t bal0 = __ballot(wl == 0);
    uint64_t bal1 = __ballot(wl == 1);
    uint64_t bal2 = __ballot(wl == 2);
    int c0n = __popcll(bal0), c1n = __popcll(bal1), c2n = __popcll(bal2);
    int off1 = c0n, off2 = c0n + c1n, off3 = off2 + c2n;
    uint64_t mym = (wl == 0) ? bal0 : (wl == 1) ? bal1 : (wl == 2) ? bal2
                                                       : ~(bal0 | bal1 | bal2);
    int base_off = (wl == 0) ? 0 : (wl == 1) ? off1 : (wl == 2) ? off2 : off3;
    int slot = base_off + (int)__popcll(mym & ((1ull << lane) - 1ull));  // 0..63

    // ---- split bf16 packing ----
    uint32_t pkh[10], pkl[10];
#pragma unroll
    for (int q = 0; q < 10; ++q) {
        float f0 = fe[2 * q], f1 = fe[2 * q + 1];
        uint32_t h0 = bf16_rne(f0), h1 = bf16_rne(f1);
        uint32_t l0 = bf16_rne(f0 - bf16_f32(h0));
        uint32_t l1 = bf16_rne(f1 - bf16_f32(h1));
        pkh[q] = h0 | (h1 << 16);
        pkl[q] = l0 | (l1 << 16);
    }
    // stage at SORTED row: hi in dwords 0..15, lo in 16..31 (pad to 36 stride).
    // zero-pad k=20..31 (A-frag is zero there, but stale LDS could be Inf/NaN).
    {
        uint32_t* row = sm + (size_t)(wv * 64 + slot) * 36;
        *(uint4*)(row)      = make_uint4(pkh[0], pkh[1], pkh[2], pkh[3]);
        *(uint4*)(row + 4)  = make_uint4(pkh[4], pkh[5], pkh[6], pkh[7]);
        *(uint4*)(row + 8)  = make_uint4(pkh[8], pkh[9], 0u, 0u);
        *(uint4*)(row + 12) = make_uint4(0u, 0u, 0u, 0u);
        *(uint4*)(row + 16) = make_uint4(pkl[0], pkl[1], pkl[2], pkl[3]);
        *(uint4*)(row + 20) = make_uint4(pkl[4], pkl[5], pkl[6], pkl[7]);
        *(uint4*)(row + 24) = make_uint4(pkl[8], pkl[9], 0u, 0u);
        *(uint4*)(row + 28) = make_uint4(0u, 0u, 0u, 0u);
    }
    // B-frags by sorted position: row wv*64 + lo16 + 16*Ct, bytes hi*16 (+64 for lo).
    // Compiler orders these after the writes (conservative LDS aliasing) with
    // lgkmcnt waits -- wave-private, no block barrier needed.
    const char* wbase = (const char*)(sm + (size_t)wv * 64 * 36);
    bf16x8 bfh0 = *(const bf16x8*)(wbase + (size_t)(lo16)      * 144 + hi * 16);
    bf16x8 bfh1 = *(const bf16x8*)(wbase + (size_t)(lo16 + 16) * 144 + hi * 16);
    bf16x8 bfh2 = *(const bf16x8*)(wbase + (size_t)(lo16 + 32) * 144 + hi * 16);
    bf16x8 bfh3 = *(const bf16x8*)(wbase + (size_t)(lo16 + 48) * 144 + hi * 16);
    bf16x8 bfl0 = *(const bf16x8*)(wbase + (size_t)(lo16)      * 144 + 64 + hi * 16);
    bf16x8 bfl1 = *(const bf16x8*)(wbase + (size_t)(lo16 + 16) * 144 + 64 + hi * 16);
    bf16x8 bfl2 = *(const bf16x8*)(wbase + (size_t)(lo16 + 32) * 144 + 64 + hi * 16);
    bf16x8 bfl3 = *(const bf16x8*)(wbase + (size_t)(lo16 + 48) * 144 + 64 + hi * 16);

    // label of a sorted position: pure register math from scalar offsets
    int lbl0 = (lo16      < off1) ? 0 : (lo16      < off2) ? 1 : (lo16      < off3) ? 2 : 3;
    int lbl1 = (lo16 + 16 < off1) ? 0 : (lo16 + 16 < off2) ? 1 : (lo16 + 16 < off3) ? 2 : 3;
    int lbl2 = (lo16 + 32 < off1) ? 0 : (lo16 + 32 < off2) ? 1 : (lo16 + 32 < off3) ? 2 : 3;
    int lbl3 = (lo16 + 48 < off1) ? 0 : (lo16 + 48 < off2) ? 1 : (lo16 + 48 < off3) ? 2 : 3;

    float oa00 = 0.f, oa01 = 0.f, oa02 = 0.f;
    float oa10 = 0.f, oa11 = 0.f, oa12 = 0.f;
    float oa20 = 0.f, oa21 = 0.f, oa22 = 0.f;
    float oa30 = 0.f, oa31 = 0.f, oa32 = 0.f;

#pragma unroll 1
    for (int m = 0; m < 3; ++m) {
        int cntm = (m == 0) ? c0n : (m == 1) ? c1n : c2n;
        if (cntm == 0) continue;                       // scalar model skip
        int lom = (m == 0) ? 0 : (m == 1) ? off1 : off2;
        int him = lom + cntm;
        const float* b1 = (m == 0) ? b1_ds : (m == 1) ? b1_dr : b1_rs;
        const float* W2 = (m == 0) ? W2_ds : (m == 1) ? W2_dr : W2_rs;

        bf16x8 afh[4], afl[4];
        f32x4 b1v[4];
        float w2v[4][12];
#pragma unroll
        for (int Ht = 0; Ht < 4; ++Ht) {
            size_t idx = (size_t)((m * 4 + Ht) * 64 + lane);
            afh[Ht] = __builtin_bit_cast(bf16x8, ((const uint4*)wf)[idx]);
            afl[Ht] = __builtin_bit_cast(bf16x8, ((const uint4*)(wf + 3072))[idx]);
            b1v[Ht] = *(const f32x4*)(b1 + 16 * Ht + 4 * hi);
            const float* w2p = W2 + (16 * Ht + 4 * hi) * 3;
            *(float4*)&w2v[Ht][0] = *(const float4*)(w2p);
            *(float4*)&w2v[Ht][4] = *(const float4*)(w2p + 4);
            *(float4*)&w2v[Ht][8] = *(const float4*)(w2p + 8);
        }
#pragma unroll
        for (int Ct = 0; Ct < 4; ++Ct) {
            // scalar presence test: does label-m interval overlap [16Ct,16Ct+16)?
            if (lom < 16 * Ct + 16 && him > 16 * Ct) {
                int lblC = (Ct == 0) ? lbl0 : (Ct == 1) ? lbl1 : (Ct == 2) ? lbl2 : lbl3;
                bf16x8 bh = (Ct == 0) ? bfh0 : (Ct == 1) ? bfh1 : (Ct == 2) ? bfh2 : bfh3;
                bf16x8 bl = (Ct == 0) ? bfl0 : (Ct == 1) ? bfl1 : (Ct == 2) ? bfl2 : bfl3;
                f32x4 acc[4];
#pragma unroll
                for (int Ht = 0; Ht < 4; ++Ht) acc[Ht] = b1v[Ht];
#pragma unroll
                for (int Ht = 0; Ht < 4; ++Ht)
                    acc[Ht] = __builtin_amdgcn_mfma_f32_16x16x32_bf16(afh[Ht], bh, acc[Ht], 0, 0, 0);
#pragma unroll
                for (int Ht = 0; Ht < 4; ++Ht)
                    acc[Ht] = __builtin_amdgcn_mfma_f32_16x16x32_bf16(afh[Ht], bl, acc[Ht], 0, 0, 0);
#pragma unroll
                for (int Ht = 0; Ht < 4; ++Ht)
                    acc[Ht] = __builtin_amdgcn_mfma_f32_16x16x32_bf16(afl[Ht], bh, acc[Ht], 0, 0, 0);
                float p0 = 0.f, p1 = 0.f, p2 = 0.f;
#pragma unroll
                for (int Ht = 0; Ht < 4; ++Ht) {
#pragma unroll
                    for (int r = 0; r < 4; ++r) {
                        float tv = tanh_fast(acc[Ht][r]);
                        p0 = fmaf(tv, w2v[Ht][r * 3 + 0], p0);
                        p1 = fmaf(tv, w2v[Ht][r * 3 + 1], p1);
                        p2 = fmaf(tv, w2v[Ht][r * 3 + 2], p2);
                    }
                }
                float sel = (lblC == m) ? 1.0f : 0.0f;
                if (Ct == 0) { oa00 = fmaf(sel, p0, oa00); oa01 = fmaf(sel, p1, oa01); oa02 = fmaf(sel, p2, oa02); }
                if (Ct == 1) { oa10 = fmaf(sel, p0, oa10); oa11 = fmaf(sel, p1, oa11); oa12 = fmaf(sel, p2, oa12); }
                if (Ct == 2) { oa20 = fmaf(sel, p0, oa20); oa21 = fmaf(sel, p1, oa21); oa22 = fmaf(sel, p2, oa22); }
                if (Ct == 3) { oa30 = fmaf(sel, p0, oa30); oa31 = fmaf(sel, p1, oa31); oa32 = fmaf(sel, p2, oa32); }
            }
        }
    }

    // ---- butterfly over hi-groups; lane L ends with flux of sorted slot L ----
    {
        float* accs[12] = {&oa00, &oa01, &oa02, &oa10, &oa11, &oa12,
                           &oa20, &oa21, &oa22, &oa30, &oa31, &oa32};
#pragma unroll
        for (int q = 0; q < 12; ++q) {
            float v = *accs[q];
            v += __shfl_xor(v, 16);
            v += __shfl_xor(v, 32);
            *accs[q] = v;
        }
    }
    float g0 = sel4(oa00, oa10, oa20, oa30, hi);
    float g1 = sel4(oa01, oa11, oa21, oa31, hi);
    float g2 = sel4(oa02, oa12, oa22, oa32, hi);

    // route back: my cell's flux sits at sorted position `slot` -> dynamic shfl
    float r0 = __shfl(g0, slot);
    float r1 = __shfl(g1, slot);
    float r2 = __shfl(g2, slot);

    float f0, f1, f2;
    if (wl < 3) {
        float bb0 = (wl == 0) ? b2_ds[0] : (wl == 1) ? b2_dr[0] : b2_rs[0];
        float bb1 = (wl == 0) ? b2_ds[1] : (wl == 1) ? b2_dr[1] : b2_rs[1];
        float bb2 = (wl == 0) ? b2_ds[2] : (wl == 1) ? b2_dr[2] : b2_rs[2];
        f0 = r0 + bb0;
        f1 = r1 + bb1;
        f2 = r2 + bb2;
    } else {
        f0 = cont ? hl0 : 0.0f;
        f1 = cont ? hl1 : 0.0f;
        f2 = cont ? hl2 : 0.0f;
    }
    if (flip) { f0 = -f0; f1 = -f1; }

    if (valid) {
        out[(size_t)cell * 3 + 0] = f0;
        out[(size_t)cell * 3 + 1] = f1;
        out[(size_t)cell * 3 + 2] = f2;
    }
}

extern "C" void kernel_launch(void* const* d_in, const int* in_sizes, int n_in,
                              void* d_out, int out_size, void* d_ws, size_t ws_size,
                              hipStream_t stream) {
    const float* P     = (const float*)d_in[0];
    const float* U     = (const float*)d_in[1];
    const float* F     = (const float*)d_in[2];
    const float* cmax  = (const float*)d_in[3];
    const float* cmin  = (const float*)d_in[4];
    const float* W1_ds = (const float*)d_in[5];
    const float* b1_ds = (const float*)d_in[6];
    const float* W2_ds = (const float*)d_in[7];
    const float* b2_ds = (const float*)d_in[8];
    const float* W1_dr = (const float*)d_in[9];
    const float* b1_dr = (const float*)d_in[10];
    const float* W2_dr = (const float*)d_in[11];
    const float* b2_dr = (const float*)d_in[12];
    const float* W1_rs = (const float*)d_in[13];
    const float* b1_rs = (const float*)d_in[14];
    const float* W2_rs = (const float*)d_in[15];
    const float* b2_rs = (const float*)d_in[16];

    int N = in_sizes[3];
    float* out = (float*)d_out;
    uint32_t* wf = (uint32_t*)d_ws;   // 24 KB: hi 12 KB + lo 12 KB

    hipLaunchKernelGGL(prep_kernel, dim3(3), dim3(256), 0, stream,
                       W1_ds, W1_dr, W1_rs, wf);

    dim3 block(256);
    dim3 grid((N + 255) / 256);
    hipLaunchKernelGGL(riemann_fused, grid, block, 0, stream,
                       P, U, F, cmax, cmin,
                       b1_ds, W2_ds, b2_ds,
                       b1_dr, W2_dr, b2_dr,
                       b1_rs, W2_rs, b2_rs,
                       wf, out, N);
}

// Round 6
// 234.449 us; speedup vs baseline: 1.9410x; 1.9410x over previous
//
#include <hip/hip_runtime.h>
#include <cstdint>

typedef __attribute__((ext_vector_type(8))) short bf16x8;
typedef __attribute__((ext_vector_type(4))) float f32x4;

__device__ __forceinline__ uint32_t bf16_rne(float f) {
    uint32_t u = __float_as_uint(f);
    u += 0x7FFFu + ((u >> 16) & 1u);
    return u >> 16;
}
__device__ __forceinline__ float bf16_f32(uint32_t h) {
    return __uint_as_float(h << 16);
}

__device__ __forceinline__ float tanh_fast(float x) {
    float e = __builtin_amdgcn_exp2f(x * 2.8853900817779268f);
    return fmaf(-2.0f, __builtin_amdgcn_rcpf(e + 1.0f), 1.0f);
}

__device__ __forceinline__ float sel4(float a, float b, float c, float d, int T) {
    float x = (T & 1) ? b : a;
    float y = (T & 1) ? d : c;
    return (T & 2) ? y : x;
}

// ---- prep: W1 (20x64 k-major) -> MFMA A-frag layout, split bf16 hi+lo ----
__global__ __launch_bounds__(256) void prep_kernel(
    const float* __restrict__ W1_0, const float* __restrict__ W1_1,
    const float* __restrict__ W1_2, uint32_t* __restrict__ wf) {
    int m = blockIdx.x;
    const float* W1 = (m == 0) ? W1_0 : (m == 1) ? W1_1 : W1_2;
    int tid = threadIdx.x;
    int Ht = tid >> 6, lane = tid & 63;
    int n = (lane & 15) + 16 * Ht;
    int kb = (lane >> 4) * 8;
    uint32_t dh[4], dl[4];
#pragma unroll
    for (int q = 0; q < 4; ++q) {
        int k0 = kb + 2 * q, k1 = k0 + 1;
        float w0 = (k0 < 20) ? W1[k0 * 64 + n] : 0.0f;
        float w1 = (k1 < 20) ? W1[k1 * 64 + n] : 0.0f;
        uint32_t h0 = bf16_rne(w0), h1 = bf16_rne(w1);
        uint32_t l0 = bf16_rne(w0 - bf16_f32(h0));
        uint32_t l1 = bf16_rne(w1 - bf16_f32(h1));
        dh[q] = h0 | (h1 << 16);
        dl[q] = l0 | (l1 << 16);
    }
    size_t idx = ((size_t)(m * 4 + Ht) * 64 + lane) * 4;
    *(uint4*)(wf + idx)        = make_uint4(dh[0], dh[1], dh[2], dh[3]);
    *(uint4*)(wf + 3072 + idx) = make_uint4(dl[0], dl[1], dl[2], dl[3]);
}

// Wave-independent version: wave-local bucket sort via ballot/popc (no LDS
// atomics, no perm arrays), single-phase hi+lo feature staging in a per-wave
// 64-row LDS region, flux routed back by one dynamic __shfl.
// ZERO __syncthreads -> waves slip freely; barrier-drain stalls eliminated.
// NOTE round-2 post-mortem: __launch_bounds__(256,4) capped VGPR at 64 ->
// massive scratch spill (FETCH 386MB / WRITE 817MB). (256,3) is the proven
// spill-free setting for this register footprint (84 VGPR in r0/r1).
__global__ __launch_bounds__(256, 3) void riemann_fused(
    const float* __restrict__ P, const float* __restrict__ U,
    const float* __restrict__ F, const float* __restrict__ cmax,
    const float* __restrict__ cmin,
    const float* __restrict__ b1_ds, const float* __restrict__ W2_ds, const float* __restrict__ b2_ds,
    const float* __restrict__ b1_dr, const float* __restrict__ W2_dr, const float* __restrict__ b2_dr,
    const float* __restrict__ b1_rs, const float* __restrict__ W2_rs, const float* __restrict__ b2_rs,
    const uint32_t* __restrict__ wf,
    float* __restrict__ out, int N) {
    __shared__ __align__(16) uint32_t sm[256 * 36];   // 36 KiB, per-wave 64-row slabs

    int tid = threadIdx.x;
    int wv = tid >> 6, lane = tid & 63;
    int hi = lane >> 4, lo16 = lane & 15;
    int cell = blockIdx.x * 256 + tid;
    bool valid = cell < N;
    int cg = valid ? cell : N - 1;

    // ---- per-cell prologue (identical to verified baseline) ----
    const float2* P2 = (const float2*)P + (size_t)cg * 3;
    const float2* U2 = (const float2*)U + (size_t)cg * 3;
    const float2* F2 = (const float2*)F + (size_t)cg * 3;
    float2 Pa = P2[0], Pb = P2[1], Pc = P2[2];
    float2 Ua = U2[0], Ub = U2[1], Uc = U2[2];
    float2 Fa = F2[0], Fb = F2[1], Fc = F2[2];
    float cm = cmax[cg];
    float cn = cmin[cg];

    bool flip = Pb.y > Pb.x;
    float fe[20];
    fe[0]  = flip ?  Pa.y :  Pa.x;
    fe[1]  = flip ?  Pa.x :  Pa.y;
    fe[2]  = flip ?  Pb.y :  Pb.x;
    fe[3]  = flip ?  Pb.x :  Pb.y;
    fe[4]  = flip ? -Pc.y :  Pc.x;
    fe[5]  = flip ? -Pc.x :  Pc.y;
    fe[6]  = flip ?  Ua.y :  Ua.x;
    fe[7]  = flip ?  Ua.x :  Ua.y;
    fe[8]  = flip ?  Ub.y :  Ub.x;
    fe[9]  = flip ?  Ub.x :  Ub.y;
    fe[10] = flip ? -Uc.y :  Uc.x;
    fe[11] = flip ? -Uc.x :  Uc.y;
    fe[12] = flip ? -Fa.y :  Fa.x;
    fe[13] = flip ? -Fa.x :  Fa.y;
    fe[14] = flip ? -Fb.y :  Fb.x;
    fe[15] = flip ? -Fb.x :  Fb.y;
    fe[16] = flip ?  Fc.y :  Fc.x;
    fe[17] = flip ?  Fc.x :  Fc.y;
    fe[18] = cm;
    fe[19] = cn;

    // cont: exact f64 compares
    double dd0 = fabs((double)fe[1] - (double)fe[0]);
    double dd1 = fabs((double)fe[3] - (double)fe[2]);
    double dd2 = fabs((double)fe[5] - (double)fe[4]);
    bool cont = fmax(fmax(dd0, dd1), dd2) < 0.005;

    // HLLE
    float inv = __builtin_amdgcn_rcpf(cm - cn);
    float cmn = cm * cn;
    float hl0 = (cm * fe[12] - cn * fe[13] + cmn * (fe[7]  - fe[6]))  * inv;
    float hl1 = (cm * fe[14] - cn * fe[15] + cmn * (fe[9]  - fe[8]))  * inv;
    float hl2 = (cm * fe[16] - cn * fe[17] + cmn * (fe[11] - fe[10])) * inv;

    // classification: f32 fast path + eps-guarded exact f64 fallback
    float c0f = __builtin_amdgcn_sqrtf(1.6666666f * fe[2] * __builtin_amdgcn_rcpf(fe[0]));
    float c1f = __builtin_amdgcn_sqrtf(1.6666666f * fe[3] * __builtin_amdgcn_rcpf(fe[1]));
    float dvf = fe[5] - fe[4];
    float numf = c0f + c1f - (1.0f / 3.0f) * dvf;
    float pz0 = __builtin_amdgcn_exp2f(-0.2f * __builtin_amdgcn_logf(fe[2]));
    float pz1 = __builtin_amdgcn_exp2f(-0.2f * __builtin_amdgcn_logf(fe[3]));
    float denf = c0f * pz0 + c1f * pz1;
    float tq = fmaxf(numf * __builtin_amdgcn_rcpf(denf), 1e-8f);
    float t2 = tq * tq;
    float psf = t2 * t2 * tq;
    float pminf = fminf(fe[2], fe[3]);
    float pmaxf = fmaxf(fe[2], fe[3]);
    float csum3 = 3.0f * (c0f + c1f);
    float vs = dvf - csum3;
    int label = (vs >= 0.0f) ? 3 : (psf < pminf ? 1 : (psf > pmaxf ? 0 : 2));

    const float eps = 2e-4f;
    bool amb = (fabsf(psf - pminf) <= eps * pminf) ||
               (fabsf(psf - pmaxf) <= eps * pmaxf) ||
               (fabsf(vs) <= eps * (fabsf(dvf) + csum3));
    if (__builtin_expect(amb, 0)) {
        double rho0 = (double)fe[0], rho1 = (double)fe[1];
        double p0   = (double)fe[2], p1   = (double)fe[3];
        double v0   = (double)fe[4], v1   = (double)fe[5];
        const double g = 5.0 / 3.0;
        double c0 = sqrt(g * p0 / rho0);
        double c1 = sqrt(g * p1 / rho1);
        double dv = v1 - v0;
        double z = (g - 1.0) / (2.0 * g);
        double num = c0 + c1 - 0.5 * (g - 1.0) * dv;
        double den = c0 / pow(p0, z) + c1 / pow(p1, z);
        double ps = pow(fmax(num / den, 1e-8), 1.0 / z);
        bool vacd = dv >= 2.0 / (g - 1.0) * (c0 + c1);
        label = vacd ? 3 : (ps < fmin(p0, p1) ? 1 : (ps > fmax(p0, p1) ? 0 : 2));
    }
    // work-label: 3 = trivial (cont override or vacuum) -> no MLP needed
    int wl = (!valid || cont || label == 3) ? 3 : label;

    // ---- wave-local bucket sort: ballots + popc, all in registers ----
    uint64_t bal0 = __ballot(wl == 0);
    uint64_t bal1 = __ballot(wl == 1);
    uint64_t bal2 = __ballot(wl == 2);
    int c0n = __popcll(bal0), c1n = __popcll(bal1), c2n = __popcll(bal2);
    int off1 = c0n, off2 = c0n + c1n, off3 = off2 + c2n;
    uint64_t mym = (wl == 0) ? bal0 : (wl == 1) ? bal1 : (wl == 2) ? bal2
                                                       : ~(bal0 | bal1 | bal2);
    int base_off = (wl == 0) ? 0 : (wl == 1) ? off1 : (wl == 2) ? off2 : off3;
    int slot = base_off + (int)__popcll(mym & ((1ull << lane) - 1ull));  // 0..63

    // ---- split bf16 packing ----
    uint32_t pkh[10], pkl[10];
#pragma unroll
    for (int q = 0; q < 10; ++q) {
        float f0 = fe[2 * q], f1 = fe[2 * q + 1];
        uint32_t h0 = bf16_rne(f0), h1 = bf16_rne(f1);
        uint32_t l0 = bf16_rne(f0 - bf16_f32(h0));
        uint32_t l1 = bf16_rne(f1 - bf16_f32(h1));
        pkh[q] = h0 | (h1 << 16);
        pkl[q] = l0 | (l1 << 16);
    }
    // stage at SORTED row: hi in dwords 0..15, lo in 16..31 (pad to 36 stride).
    // zero-pad k=20..31 (A-frag is zero there, but stale LDS could be Inf/NaN).
    {
        uint32_t* row = sm + (size_t)(wv * 64 + slot) * 36;
        *(uint4*)(row)      = make_uint4(pkh[0], pkh[1], pkh[2], pkh[3]);
        *(uint4*)(row + 4)  = make_uint4(pkh[4], pkh[5], pkh[6], pkh[7]);
        *(uint4*)(row + 8)  = make_uint4(pkh[8], pkh[9], 0u, 0u);
        *(uint4*)(row + 12) = make_uint4(0u, 0u, 0u, 0u);
        *(uint4*)(row + 16) = make_uint4(pkl[0], pkl[1], pkl[2], pkl[3]);
        *(uint4*)(row + 20) = make_uint4(pkl[4], pkl[5], pkl[6], pkl[7]);
        *(uint4*)(row + 24) = make_uint4(pkl[8], pkl[9], 0u, 0u);
        *(uint4*)(row + 28) = make_uint4(0u, 0u, 0u, 0u);
    }
    // B-frags by sorted position: row wv*64 + lo16 + 16*Ct, bytes hi*16 (+64 for lo).
    // Compiler orders these after the writes (conservative LDS aliasing) with
    // lgkmcnt waits -- wave-private, no block barrier needed.
    const char* wbase = (const char*)(sm + (size_t)wv * 64 * 36);
    bf16x8 bfh0 = *(const bf16x8*)(wbase + (size_t)(lo16)      * 144 + hi * 16);
    bf16x8 bfh1 = *(const bf16x8*)(wbase + (size_t)(lo16 + 16) * 144 + hi * 16);
    bf16x8 bfh2 = *(const bf16x8*)(wbase + (size_t)(lo16 + 32) * 144 + hi * 16);
    bf16x8 bfh3 = *(const bf16x8*)(wbase + (size_t)(lo16 + 48) * 144 + hi * 16);
    bf16x8 bfl0 = *(const bf16x8*)(wbase + (size_t)(lo16)      * 144 + 64 + hi * 16);
    bf16x8 bfl1 = *(const bf16x8*)(wbase + (size_t)(lo16 + 16) * 144 + 64 + hi * 16);
    bf16x8 bfl2 = *(const bf16x8*)(wbase + (size_t)(lo16 + 32) * 144 + 64 + hi * 16);
    bf16x8 bfl3 = *(const bf16x8*)(wbase + (size_t)(lo16 + 48) * 144 + 64 + hi * 16);

    // label of a sorted position: pure register math from scalar offsets
    int lbl0 = (lo16      < off1) ? 0 : (lo16      < off2) ? 1 : (lo16      < off3) ? 2 : 3;
    int lbl1 = (lo16 + 16 < off1) ? 0 : (lo16 + 16 < off2) ? 1 : (lo16 + 16 < off3) ? 2 : 3;
    int lbl2 = (lo16 + 32 < off1) ? 0 : (lo16 + 32 < off2) ? 1 : (lo16 + 32 < off3) ? 2 : 3;
    int lbl3 = (lo16 + 48 < off1) ? 0 : (lo16 + 48 < off2) ? 1 : (lo16 + 48 < off3) ? 2 : 3;

    float oa00 = 0.f, oa01 = 0.f, oa02 = 0.f;
    float oa10 = 0.f, oa11 = 0.f, oa12 = 0.f;
    float oa20 = 0.f, oa21 = 0.f, oa22 = 0.f;
    float oa30 = 0.f, oa31 = 0.f, oa32 = 0.f;

#pragma unroll 1
    for (int m = 0; m < 3; ++m) {
        int cntm = (m == 0) ? c0n : (m == 1) ? c1n : c2n;
        if (cntm == 0) continue;                       // scalar model skip
        int lom = (m == 0) ? 0 : (m == 1) ? off1 : off2;
        int him = lom + cntm;
        const float* b1 = (m == 0) ? b1_ds : (m == 1) ? b1_dr : b1_rs;
        const float* W2 = (m == 0) ? W2_ds : (m == 1) ? W2_dr : W2_rs;

        bf16x8 afh[4], afl[4];
        f32x4 b1v[4];
        float w2v[4][12];
#pragma unroll
        for (int Ht = 0; Ht < 4; ++Ht) {
            size_t idx = (size_t)((m * 4 + Ht) * 64 + lane);
            afh[Ht] = __builtin_bit_cast(bf16x8, ((const uint4*)wf)[idx]);
            afl[Ht] = __builtin_bit_cast(bf16x8, ((const uint4*)(wf + 3072))[idx]);
            b1v[Ht] = *(const f32x4*)(b1 + 16 * Ht + 4 * hi);
            const float* w2p = W2 + (16 * Ht + 4 * hi) * 3;
            *(float4*)&w2v[Ht][0] = *(const float4*)(w2p);
            *(float4*)&w2v[Ht][4] = *(const float4*)(w2p + 4);
            *(float4*)&w2v[Ht][8] = *(const float4*)(w2p + 8);
        }
#pragma unroll
        for (int Ct = 0; Ct < 4; ++Ct) {
            // scalar presence test: does label-m interval overlap [16Ct,16Ct+16)?
            if (lom < 16 * Ct + 16 && him > 16 * Ct) {
                int lblC = (Ct == 0) ? lbl0 : (Ct == 1) ? lbl1 : (Ct == 2) ? lbl2 : lbl3;
                bf16x8 bh = (Ct == 0) ? bfh0 : (Ct == 1) ? bfh1 : (Ct == 2) ? bfh2 : bfh3;
                bf16x8 bl = (Ct == 0) ? bfl0 : (Ct == 1) ? bfl1 : (Ct == 2) ? bfl2 : bfl3;
                f32x4 acc[4];
#pragma unroll
                for (int Ht = 0; Ht < 4; ++Ht) acc[Ht] = b1v[Ht];
#pragma unroll
                for (int Ht = 0; Ht < 4; ++Ht)
                    acc[Ht] = __builtin_amdgcn_mfma_f32_16x16x32_bf16(afh[Ht], bh, acc[Ht], 0, 0, 0);
#pragma unroll
                for (int Ht = 0; Ht < 4; ++Ht)
                    acc[Ht] = __builtin_amdgcn_mfma_f32_16x16x32_bf16(afh[Ht], bl, acc[Ht], 0, 0, 0);
#pragma unroll
                for (int Ht = 0; Ht < 4; ++Ht)
                    acc[Ht] = __builtin_amdgcn_mfma_f32_16x16x32_bf16(afl[Ht], bh, acc[Ht], 0, 0, 0);
                float p0 = 0.f, p1 = 0.f, p2 = 0.f;
#pragma unroll
                for (int Ht = 0; Ht < 4; ++Ht) {
#pragma unroll
                    for (int r = 0; r < 4; ++r) {
                        float tv = tanh_fast(acc[Ht][r]);
                        p0 = fmaf(tv, w2v[Ht][r * 3 + 0], p0);
                        p1 = fmaf(tv, w2v[Ht][r * 3 + 1], p1);
                        p2 = fmaf(tv, w2v[Ht][r * 3 + 2], p2);
                    }
                }
                float sel = (lblC == m) ? 1.0f : 0.0f;
                if (Ct == 0) { oa00 = fmaf(sel, p0, oa00); oa01 = fmaf(sel, p1, oa01); oa02 = fmaf(sel, p2, oa02); }
                if (Ct == 1) { oa10 = fmaf(sel, p0, oa10); oa11 = fmaf(sel, p1, oa11); oa12 = fmaf(sel, p2, oa12); }
                if (Ct == 2) { oa20 = fmaf(sel, p0, oa20); oa21 = fmaf(sel, p1, oa21); oa22 = fmaf(sel, p2, oa22); }
                if (Ct == 3) { oa30 = fmaf(sel, p0, oa30); oa31 = fmaf(sel, p1, oa31); oa32 = fmaf(sel, p2, oa32); }
            }
        }
    }

    // ---- butterfly over hi-groups; lane L ends with flux of sorted slot L ----
    {
        float* accs[12] = {&oa00, &oa01, &oa02, &oa10, &oa11, &oa12,
                           &oa20, &oa21, &oa22, &oa30, &oa31, &oa32};
#pragma unroll
        for (int q = 0; q < 12; ++q) {
            float v = *accs[q];
            v += __shfl_xor(v, 16);
            v += __shfl_xor(v, 32);
            *accs[q] = v;
        }
    }
    float g0 = sel4(oa00, oa10, oa20, oa30, hi);
    float g1 = sel4(oa01, oa11, oa21, oa31, hi);
    float g2 = sel4(oa02, oa12, oa22, oa32, hi);

    // route back: my cell's flux sits at sorted position `slot` -> dynamic shfl
    float r0 = __shfl(g0, slot);
    float r1 = __shfl(g1, slot);
    float r2 = __shfl(g2, slot);

    float f0, f1, f2;
    if (wl < 3) {
        float bb0 = (wl == 0) ? b2_ds[0] : (wl == 1) ? b2_dr[0] : b2_rs[0];
        float bb1 = (wl == 0) ? b2_ds[1] : (wl == 1) ? b2_dr[1] : b2_rs[1];
        float bb2 = (wl == 0) ? b2_ds[2] : (wl == 1) ? b2_dr[2] : b2_rs[2];
        f0 = r0 + bb0;
        f1 = r1 + bb1;
        f2 = r2 + bb2;
    } else {
        f0 = cont ? hl0 : 0.0f;
        f1 = cont ? hl1 : 0.0f;
        f2 = cont ? hl2 : 0.0f;
    }
    if (flip) { f0 = -f0; f1 = -f1; }

    if (valid) {
        out[(size_t)cell * 3 + 0] = f0;
        out[(size_t)cell * 3 + 1] = f1;
        out[(size_t)cell * 3 + 2] = f2;
    }
}

extern "C" void kernel_launch(void* const* d_in, const int* in_sizes, int n_in,
                              void* d_out, int out_size, void* d_ws, size_t ws_size,
                              hipStream_t stream) {
    const float* P     = (const float*)d_in[0];
    const float* U     = (const float*)d_in[1];
    const float* F     = (const float*)d_in[2];
    const float* cmax  = (const float*)d_in[3];
    const float* cmin  = (const float*)d_in[4];
    const float* W1_ds = (const float*)d_in[5];
    const float* b1_ds = (const float*)d_in[6];
    const float* W2_ds = (const float*)d_in[7];
    const float* b2_ds = (const float*)d_in[8];
    const float* W1_dr = (const float*)d_in[9];
    const float* b1_dr = (const float*)d_in[10];
    const float* W2_dr = (const float*)d_in[11];
    const float* b2_dr = (const float*)d_in[12];
    const float* W1_rs = (const float*)d_in[13];
    const float* b1_rs = (const float*)d_in[14];
    const float* W2_rs = (const float*)d_in[15];
    const float* b2_rs = (const float*)d_in[16];

    int N = in_sizes[3];
    float* out = (float*)d_out;
    uint32_t* wf = (uint32_t*)d_ws;   // 24 KB: hi 12 KB + lo 12 KB

    hipLaunchKernelGGL(prep_kernel, dim3(3), dim3(256), 0, stream,
                       W1_ds, W1_dr, W1_rs, wf);

    dim3 block(256);
    dim3 grid((N + 255) / 256);
    hipLaunchKernelGGL(riemann_fused, grid, block, 0, stream,
                       P, U, F, cmax, cmin,
                       b1_ds, W2_ds, b2_ds,
                       b1_dr, W2_dr, b2_dr,
                       b1_rs, W2_rs, b2_rs,
                       wf, out, N);
}

// Round 7
// 231.602 us; speedup vs baseline: 1.9648x; 1.0123x over previous
//
#include <hip/hip_runtime.h>
#include <cstdint>

typedef __attribute__((ext_vector_type(8))) short bf16x8;
typedef __attribute__((ext_vector_type(4))) float f32x4;

__device__ __forceinline__ uint32_t bf16_rne(float f) {
    uint32_t u = __float_as_uint(f);
    u += 0x7FFFu + ((u >> 16) & 1u);
    return u >> 16;
}
__device__ __forceinline__ float bf16_f32(uint32_t h) {
    return __uint_as_float(h << 16);
}

__device__ __forceinline__ float tanh_fast(float x) {
    float e = __builtin_amdgcn_exp2f(x * 2.8853900817779268f);
    return fmaf(-2.0f, __builtin_amdgcn_rcpf(e + 1.0f), 1.0f);
}

__device__ __forceinline__ float sel4(float a, float b, float c, float d, int T) {
    float x = (T & 1) ? b : a;
    float y = (T & 1) ? d : c;
    return (T & 2) ? y : x;
}

// ---- prep: W1 (20x64 k-major) -> MFMA A-frag layout, split bf16 hi+lo ----
__global__ __launch_bounds__(256) void prep_kernel(
    const float* __restrict__ W1_0, const float* __restrict__ W1_1,
    const float* __restrict__ W1_2, uint32_t* __restrict__ wf) {
    int m = blockIdx.x;
    const float* W1 = (m == 0) ? W1_0 : (m == 1) ? W1_1 : W1_2;
    int tid = threadIdx.x;
    int Ht = tid >> 6, lane = tid & 63;
    int n = (lane & 15) + 16 * Ht;
    int kb = (lane >> 4) * 8;
    uint32_t dh[4], dl[4];
#pragma unroll
    for (int q = 0; q < 4; ++q) {
        int k0 = kb + 2 * q, k1 = k0 + 1;
        float w0 = (k0 < 20) ? W1[k0 * 64 + n] : 0.0f;
        float w1 = (k1 < 20) ? W1[k1 * 64 + n] : 0.0f;
        uint32_t h0 = bf16_rne(w0), h1 = bf16_rne(w1);
        uint32_t l0 = bf16_rne(w0 - bf16_f32(h0));
        uint32_t l1 = bf16_rne(w1 - bf16_f32(h1));
        dh[q] = h0 | (h1 << 16);
        dl[q] = l0 | (l1 << 16);
    }
    size_t idx = ((size_t)(m * 4 + Ht) * 64 + lane) * 4;
    *(uint4*)(wf + idx)        = make_uint4(dh[0], dh[1], dh[2], dh[3]);
    *(uint4*)(wf + 3072 + idx) = make_uint4(dl[0], dl[1], dl[2], dl[3]);
}

// HYBRID (r7): block-wide bucket sort (r0's model locality) computed via
// per-wave ballots + a 16-int LDS count exchange (r6's machinery).
// - no LDS atomics (r0 had 512 serialized atomicAdd-with-return on 4 addrs)
// - no perm/label arrays (slot + thresholds in registers)
// - single-phase hi+lo staging at sorted row, stride 36 dwords (r6-verified)
// - 4 barriers total (r0 had 8)
// Numerics bit-identical to r0/r6 (same rne pack, same 3-pass MFMA order).
__global__ __launch_bounds__(256, 3) void riemann_fused(
    const float* __restrict__ P, const float* __restrict__ U,
    const float* __restrict__ F, const float* __restrict__ cmax,
    const float* __restrict__ cmin,
    const float* __restrict__ b1_ds, const float* __restrict__ W2_ds, const float* __restrict__ b2_ds,
    const float* __restrict__ b1_dr, const float* __restrict__ W2_dr, const float* __restrict__ b2_dr,
    const float* __restrict__ b1_rs, const float* __restrict__ W2_rs, const float* __restrict__ b2_rs,
    const uint32_t* __restrict__ wf,
    float* __restrict__ out, int N) {
    __shared__ __align__(16) uint32_t sm[256 * 36];   // 36 KiB: feats, later flux
    __shared__ int s_cnt[4][4];                       // [wave][label]

    int tid = threadIdx.x;
    int wv = tid >> 6, lane = tid & 63;
    int hi = lane >> 4, lo16 = lane & 15;
    int cell = blockIdx.x * 256 + tid;
    bool valid = cell < N;
    int cg = valid ? cell : N - 1;

    // ---- per-cell prologue (identical to verified baseline) ----
    const float2* P2 = (const float2*)P + (size_t)cg * 3;
    const float2* U2 = (const float2*)U + (size_t)cg * 3;
    const float2* F2 = (const float2*)F + (size_t)cg * 3;
    float2 Pa = P2[0], Pb = P2[1], Pc = P2[2];
    float2 Ua = U2[0], Ub = U2[1], Uc = U2[2];
    float2 Fa = F2[0], Fb = F2[1], Fc = F2[2];
    float cm = cmax[cg];
    float cn = cmin[cg];

    bool flip = Pb.y > Pb.x;
    float fe[20];
    fe[0]  = flip ?  Pa.y :  Pa.x;
    fe[1]  = flip ?  Pa.x :  Pa.y;
    fe[2]  = flip ?  Pb.y :  Pb.x;
    fe[3]  = flip ?  Pb.x :  Pb.y;
    fe[4]  = flip ? -Pc.y :  Pc.x;
    fe[5]  = flip ? -Pc.x :  Pc.y;
    fe[6]  = flip ?  Ua.y :  Ua.x;
    fe[7]  = flip ?  Ua.x :  Ua.y;
    fe[8]  = flip ?  Ub.y :  Ub.x;
    fe[9]  = flip ?  Ub.x :  Ub.y;
    fe[10] = flip ? -Uc.y :  Uc.x;
    fe[11] = flip ? -Uc.x :  Uc.y;
    fe[12] = flip ? -Fa.y :  Fa.x;
    fe[13] = flip ? -Fa.x :  Fa.y;
    fe[14] = flip ? -Fb.y :  Fb.x;
    fe[15] = flip ? -Fb.x :  Fb.y;
    fe[16] = flip ?  Fc.y :  Fc.x;
    fe[17] = flip ?  Fc.x :  Fc.y;
    fe[18] = cm;
    fe[19] = cn;

    // cont: exact f64 compares
    double dd0 = fabs((double)fe[1] - (double)fe[0]);
    double dd1 = fabs((double)fe[3] - (double)fe[2]);
    double dd2 = fabs((double)fe[5] - (double)fe[4]);
    bool cont = fmax(fmax(dd0, dd1), dd2) < 0.005;

    // HLLE
    float inv = __builtin_amdgcn_rcpf(cm - cn);
    float cmn = cm * cn;
    float hl0 = (cm * fe[12] - cn * fe[13] + cmn * (fe[7]  - fe[6]))  * inv;
    float hl1 = (cm * fe[14] - cn * fe[15] + cmn * (fe[9]  - fe[8]))  * inv;
    float hl2 = (cm * fe[16] - cn * fe[17] + cmn * (fe[11] - fe[10])) * inv;

    // classification: f32 fast path + eps-guarded exact f64 fallback
    float c0f = __builtin_amdgcn_sqrtf(1.6666666f * fe[2] * __builtin_amdgcn_rcpf(fe[0]));
    float c1f = __builtin_amdgcn_sqrtf(1.6666666f * fe[3] * __builtin_amdgcn_rcpf(fe[1]));
    float dvf = fe[5] - fe[4];
    float numf = c0f + c1f - (1.0f / 3.0f) * dvf;
    float pz0 = __builtin_amdgcn_exp2f(-0.2f * __builtin_amdgcn_logf(fe[2]));
    float pz1 = __builtin_amdgcn_exp2f(-0.2f * __builtin_amdgcn_logf(fe[3]));
    float denf = c0f * pz0 + c1f * pz1;
    float tq = fmaxf(numf * __builtin_amdgcn_rcpf(denf), 1e-8f);
    float t2 = tq * tq;
    float psf = t2 * t2 * tq;
    float pminf = fminf(fe[2], fe[3]);
    float pmaxf = fmaxf(fe[2], fe[3]);
    float csum3 = 3.0f * (c0f + c1f);
    float vs = dvf - csum3;
    int label = (vs >= 0.0f) ? 3 : (psf < pminf ? 1 : (psf > pmaxf ? 0 : 2));

    const float eps = 2e-4f;
    bool amb = (fabsf(psf - pminf) <= eps * pminf) ||
               (fabsf(psf - pmaxf) <= eps * pmaxf) ||
               (fabsf(vs) <= eps * (fabsf(dvf) + csum3));
    if (__builtin_expect(amb, 0)) {
        double rho0 = (double)fe[0], rho1 = (double)fe[1];
        double p0   = (double)fe[2], p1   = (double)fe[3];
        double v0   = (double)fe[4], v1   = (double)fe[5];
        const double g = 5.0 / 3.0;
        double c0 = sqrt(g * p0 / rho0);
        double c1 = sqrt(g * p1 / rho1);
        double dv = v1 - v0;
        double z = (g - 1.0) / (2.0 * g);
        double num = c0 + c1 - 0.5 * (g - 1.0) * dv;
        double den = c0 / pow(p0, z) + c1 / pow(p1, z);
        double ps = pow(fmax(num / den, 1e-8), 1.0 / z);
        bool vacd = dv >= 2.0 / (g - 1.0) * (c0 + c1);
        label = vacd ? 3 : (ps < fmin(p0, p1) ? 1 : (ps > fmax(p0, p1) ? 0 : 2));
    }
    // work-label: 3 = trivial (cont override or vacuum) -> no MLP needed
    int wl = (!valid || cont || label == 3) ? 3 : label;

    // ---- block-wide bucket sort via ballots + 16-count exchange ----
    uint64_t bal0 = __ballot(wl == 0);
    uint64_t bal1 = __ballot(wl == 1);
    uint64_t bal2 = __ballot(wl == 2);
    int c0n = __popcll(bal0), c1n = __popcll(bal1), c2n = __popcll(bal2);
    uint64_t mym = (wl == 0) ? bal0 : (wl == 1) ? bal1 : (wl == 2) ? bal2
                                                       : ~(bal0 | bal1 | bal2);
    int rank = (int)__popcll(mym & ((1ull << lane) - 1ull));
    if (lane < 4) {
        int c = (lane == 0) ? c0n : (lane == 1) ? c1n : (lane == 2) ? c2n
                                                      : (64 - c0n - c1n - c2n);
        s_cnt[wv][lane] = c;
    }
    __syncthreads();                               // B1: counts visible
    int T0 = s_cnt[0][0] + s_cnt[1][0] + s_cnt[2][0] + s_cnt[3][0];
    int T1 = s_cnt[0][1] + s_cnt[1][1] + s_cnt[2][1] + s_cnt[3][1];
    int T2 = s_cnt[0][2] + s_cnt[1][2] + s_cnt[2][2] + s_cnt[3][2];
    int off1 = T0, off2 = T0 + T1, off3 = T0 + T1 + T2;   // block thresholds
    int basew = (wl == 0) ? 0 : (wl == 1) ? off1 : (wl == 2) ? off2 : off3;
    int prev = 0;
    if (wv > 0) prev += s_cnt[0][wl];
    if (wv > 1) prev += s_cnt[1][wl];
    if (wv > 2) prev += s_cnt[2][wl];
    int slot = basew + prev + rank;                // 0..255, block-wide sorted

    // ---- split bf16 packing ----
    uint32_t pkh[10], pkl[10];
#pragma unroll
    for (int q = 0; q < 10; ++q) {
        float f0 = fe[2 * q], f1 = fe[2 * q + 1];
        uint32_t h0 = bf16_rne(f0), h1 = bf16_rne(f1);
        uint32_t l0 = bf16_rne(f0 - bf16_f32(h0));
        uint32_t l1 = bf16_rne(f1 - bf16_f32(h1));
        pkh[q] = h0 | (h1 << 16);
        pkl[q] = l0 | (l1 << 16);
    }
    // stage at SORTED row (block-wide): hi dwords 0..15, lo 16..31, stride 36
    {
        uint32_t* row = sm + (size_t)slot * 36;
        *(uint4*)(row)      = make_uint4(pkh[0], pkh[1], pkh[2], pkh[3]);
        *(uint4*)(row + 4)  = make_uint4(pkh[4], pkh[5], pkh[6], pkh[7]);
        *(uint4*)(row + 8)  = make_uint4(pkh[8], pkh[9], 0u, 0u);
        *(uint4*)(row + 12) = make_uint4(0u, 0u, 0u, 0u);
        *(uint4*)(row + 16) = make_uint4(pkl[0], pkl[1], pkl[2], pkl[3]);
        *(uint4*)(row + 20) = make_uint4(pkl[4], pkl[5], pkl[6], pkl[7]);
        *(uint4*)(row + 24) = make_uint4(pkl[8], pkl[9], 0u, 0u);
        *(uint4*)(row + 28) = make_uint4(0u, 0u, 0u, 0u);
    }
    __syncthreads();                               // B2: feats staged

    // B-frags: wave's window rows wv*64 + lo16 + 16*Ct (cross-wave data OK)
    int r0w = wv * 64 + lo16;
    const char* sbase = (const char*)sm;
    bf16x8 bfh0 = *(const bf16x8*)(sbase + (size_t)(r0w)      * 144 + hi * 16);
    bf16x8 bfh1 = *(const bf16x8*)(sbase + (size_t)(r0w + 16) * 144 + hi * 16);
    bf16x8 bfh2 = *(const bf16x8*)(sbase + (size_t)(r0w + 32) * 144 + hi * 16);
    bf16x8 bfh3 = *(const bf16x8*)(sbase + (size_t)(r0w + 48) * 144 + hi * 16);
    bf16x8 bfl0 = *(const bf16x8*)(sbase + (size_t)(r0w)      * 144 + 64 + hi * 16);
    bf16x8 bfl1 = *(const bf16x8*)(sbase + (size_t)(r0w + 16) * 144 + 64 + hi * 16);
    bf16x8 bfl2 = *(const bf16x8*)(sbase + (size_t)(r0w + 32) * 144 + 64 + hi * 16);
    bf16x8 bfl3 = *(const bf16x8*)(sbase + (size_t)(r0w + 48) * 144 + 64 + hi * 16);
    __syncthreads();                               // B3: all feat reads done

    // label of sorted positions from block thresholds (register math)
    int lbl0 = (r0w      < off1) ? 0 : (r0w      < off2) ? 1 : (r0w      < off3) ? 2 : 3;
    int lbl1 = (r0w + 16 < off1) ? 0 : (r0w + 16 < off2) ? 1 : (r0w + 16 < off3) ? 2 : 3;
    int lbl2 = (r0w + 32 < off1) ? 0 : (r0w + 32 < off2) ? 1 : (r0w + 32 < off3) ? 2 : 3;
    int lbl3 = (r0w + 48 < off1) ? 0 : (r0w + 48 < off2) ? 1 : (r0w + 48 < off3) ? 2 : 3;

    float oa00 = 0.f, oa01 = 0.f, oa02 = 0.f;
    float oa10 = 0.f, oa11 = 0.f, oa12 = 0.f;
    float oa20 = 0.f, oa21 = 0.f, oa22 = 0.f;
    float oa30 = 0.f, oa31 = 0.f, oa32 = 0.f;

    int wbeg = wv * 64, wend = wbeg + 64;
#pragma unroll 1
    for (int m = 0; m < 3; ++m) {
        int mlo = (m == 0) ? 0 : (m == 1) ? off1 : off2;
        int mhi = (m == 0) ? off1 : (m == 1) ? off2 : off3;
        if (mhi <= wbeg || mlo >= wend) continue;  // wave-uniform model skip
        const float* b1 = (m == 0) ? b1_ds : (m == 1) ? b1_dr : b1_rs;
        const float* W2 = (m == 0) ? W2_ds : (m == 1) ? W2_dr : W2_rs;

        bf16x8 afh[4], afl[4];
        f32x4 b1v[4];
        float w2v[4][12];
#pragma unroll
        for (int Ht = 0; Ht < 4; ++Ht) {
            size_t idx = (size_t)((m * 4 + Ht) * 64 + lane);
            afh[Ht] = __builtin_bit_cast(bf16x8, ((const uint4*)wf)[idx]);
            afl[Ht] = __builtin_bit_cast(bf16x8, ((const uint4*)(wf + 3072))[idx]);
            b1v[Ht] = *(const f32x4*)(b1 + 16 * Ht + 4 * hi);
            const float* w2p = W2 + (16 * Ht + 4 * hi) * 3;
            *(float4*)&w2v[Ht][0] = *(const float4*)(w2p);
            *(float4*)&w2v[Ht][4] = *(const float4*)(w2p + 4);
            *(float4*)&w2v[Ht][8] = *(const float4*)(w2p + 8);
        }
#pragma unroll
        for (int Ct = 0; Ct < 4; ++Ct) {
            int tb = wbeg + 16 * Ct;
            // does label-m interval [mlo,mhi) overlap tile [tb,tb+16)?
            if (mlo < tb + 16 && mhi > tb) {
                int lblC = (Ct == 0) ? lbl0 : (Ct == 1) ? lbl1 : (Ct == 2) ? lbl2 : lbl3;
                bf16x8 bh = (Ct == 0) ? bfh0 : (Ct == 1) ? bfh1 : (Ct == 2) ? bfh2 : bfh3;
                bf16x8 bl = (Ct == 0) ? bfl0 : (Ct == 1) ? bfl1 : (Ct == 2) ? bfl2 : bfl3;
                f32x4 acc[4];
#pragma unroll
                for (int Ht = 0; Ht < 4; ++Ht) acc[Ht] = b1v[Ht];
#pragma unroll
                for (int Ht = 0; Ht < 4; ++Ht)
                    acc[Ht] = __builtin_amdgcn_mfma_f32_16x16x32_bf16(afh[Ht], bh, acc[Ht], 0, 0, 0);
#pragma unroll
                for (int Ht = 0; Ht < 4; ++Ht)
                    acc[Ht] = __builtin_amdgcn_mfma_f32_16x16x32_bf16(afh[Ht], bl, acc[Ht], 0, 0, 0);
#pragma unroll
                for (int Ht = 0; Ht < 4; ++Ht)
                    acc[Ht] = __builtin_amdgcn_mfma_f32_16x16x32_bf16(afl[Ht], bh, acc[Ht], 0, 0, 0);
                float p0 = 0.f, p1 = 0.f, p2 = 0.f;
#pragma unroll
                for (int Ht = 0; Ht < 4; ++Ht) {
#pragma unroll
                    for (int r = 0; r < 4; ++r) {
                        float tv = tanh_fast(acc[Ht][r]);
                        p0 = fmaf(tv, w2v[Ht][r * 3 + 0], p0);
                        p1 = fmaf(tv, w2v[Ht][r * 3 + 1], p1);
                        p2 = fmaf(tv, w2v[Ht][r * 3 + 2], p2);
                    }
                }
                float sel = (lblC == m) ? 1.0f : 0.0f;
                if (Ct == 0) { oa00 = fmaf(sel, p0, oa00); oa01 = fmaf(sel, p1, oa01); oa02 = fmaf(sel, p2, oa02); }
                if (Ct == 1) { oa10 = fmaf(sel, p0, oa10); oa11 = fmaf(sel, p1, oa11); oa12 = fmaf(sel, p2, oa12); }
                if (Ct == 2) { oa20 = fmaf(sel, p0, oa20); oa21 = fmaf(sel, p1, oa21); oa22 = fmaf(sel, p2, oa22); }
                if (Ct == 3) { oa30 = fmaf(sel, p0, oa30); oa31 = fmaf(sel, p1, oa31); oa32 = fmaf(sel, p2, oa32); }
            }
        }
    }

    // ---- butterfly over hi-groups; lane L ends with flux of sorted slot wbeg+L
    {
        float* accs[12] = {&oa00, &oa01, &oa02, &oa10, &oa11, &oa12,
                           &oa20, &oa21, &oa22, &oa30, &oa31, &oa32};
#pragma unroll
        for (int q = 0; q < 12; ++q) {
            float v = *accs[q];
            v += __shfl_xor(v, 16);
            v += __shfl_xor(v, 32);
            *accs[q] = v;
        }
    }
    float g0 = sel4(oa00, oa10, oa20, oa30, hi);
    float g1 = sel4(oa01, oa11, oa21, oa31, hi);
    float g2 = sel4(oa02, oa12, oa22, oa32, hi);

    // route back: write flux at sorted position, read own slot (cross-wave)
    float (*sm_flux)[3] = (float (*)[3])sm;        // aliases feats (post-B3)
    sm_flux[wbeg + lane][0] = g0;
    sm_flux[wbeg + lane][1] = g1;
    sm_flux[wbeg + lane][2] = g2;
    __syncthreads();                               // B4: flux visible

    float f0, f1, f2;
    if (wl < 3) {
        float bb0 = (wl == 0) ? b2_ds[0] : (wl == 1) ? b2_dr[0] : b2_rs[0];
        float bb1 = (wl == 0) ? b2_ds[1] : (wl == 1) ? b2_dr[1] : b2_rs[1];
        float bb2 = (wl == 0) ? b2_ds[2] : (wl == 1) ? b2_dr[2] : b2_rs[2];
        f0 = sm_flux[slot][0] + bb0;
        f1 = sm_flux[slot][1] + bb1;
        f2 = sm_flux[slot][2] + bb2;
    } else {
        f0 = cont ? hl0 : 0.0f;
        f1 = cont ? hl1 : 0.0f;
        f2 = cont ? hl2 : 0.0f;
    }
    if (flip) { f0 = -f0; f1 = -f1; }

    if (valid) {
        out[(size_t)cell * 3 + 0] = f0;
        out[(size_t)cell * 3 + 1] = f1;
        out[(size_t)cell * 3 + 2] = f2;
    }
}

extern "C" void kernel_launch(void* const* d_in, const int* in_sizes, int n_in,
                              void* d_out, int out_size, void* d_ws, size_t ws_size,
                              hipStream_t stream) {
    const float* P     = (const float*)d_in[0];
    const float* U     = (const float*)d_in[1];
    const float* F     = (const float*)d_in[2];
    const float* cmax  = (const float*)d_in[3];
    const float* cmin  = (const float*)d_in[4];
    const float* W1_ds = (const float*)d_in[5];
    const float* b1_ds = (const float*)d_in[6];
    const float* W2_ds = (const float*)d_in[7];
    const float* b2_ds = (const float*)d_in[8];
    const float* W1_dr = (const float*)d_in[9];
    const float* b1_dr = (const float*)d_in[10];
    const float* W2_dr = (const float*)d_in[11];
    const float* b2_dr = (const float*)d_in[12];
    const float* W1_rs = (const float*)d_in[13];
    const float* b1_rs = (const float*)d_in[14];
    const float* W2_rs = (const float*)d_in[15];
    const float* b2_rs = (const float*)d_in[16];

    int N = in_sizes[3];
    float* out = (float*)d_out;
    uint32_t* wf = (uint32_t*)d_ws;   // 24 KB: hi 12 KB + lo 12 KB

    hipLaunchKernelGGL(prep_kernel, dim3(3), dim3(256), 0, stream,
                       W1_ds, W1_dr, W1_rs, wf);

    dim3 block(256);
    dim3 grid((N + 255) / 256);
    hipLaunchKernelGGL(riemann_fused, grid, block, 0, stream,
                       P, U, F, cmax, cmin,
                       b1_ds, W2_ds, b2_ds,
                       b1_dr, W2_dr, b2_dr,
                       b1_rs, W2_rs, b2_rs,
                       wf, out, N);
}